// Round 14
// baseline (21847.435 us; speedup 1.0000x reference)
//
#include <hip/hip_runtime.h>
#include <hip/hip_bf16.h>
#include <hip/hip_cooperative_groups.h>
#include <math.h>

namespace cg = cooperative_groups;

#define T_ 512
#define B_ 64
#define E_ 256
#define H_ 600
#define G4 2400    // 4*H
#define MTOT 32768 // T*B
#define KP1 1216   // padded K for layer 1 (38*32)
#define GSTR (38 * 19 * 512)  // per-gate packed Whh stride (ushorts)
#define PARS (2 * 64 * 608)   // ushorts per h-parity buffer

typedef __attribute__((ext_vector_type(8))) short bf16x8;
typedef __attribute__((ext_vector_type(4))) float f32x4;

static __device__ __forceinline__ ushort f2bf(float x) {
    unsigned u = __builtin_bit_cast(unsigned, x);
    unsigned r = (u + 0x7FFFu + ((u >> 16) & 1u)) >> 16;
    return (ushort)r;
}
static __device__ __forceinline__ float bf2f(ushort h) {
    unsigned u = ((unsigned)h) << 16;
    return __builtin_bit_cast(float, u);
}

// ---------------- generic zero
__global__ __launch_bounds__(256) void zero_kernel(float* __restrict__ p, int n) {
    int i = blockIdx.x * 256 + threadIdx.x;
    if (i < n) p[i] = 0.f;
}

// ---------------- embedding gather + bf16: xh[m][k], m = t*64+b
__global__ __launch_bounds__(256) void xsplit(const int* __restrict__ us,
                                              const float* __restrict__ embed,
                                              ushort* __restrict__ xh) {
    int m = blockIdx.x;
    int t = m >> 6, b = m & 63;
    int tok = us[b * T_ + t];
    int k = threadIdx.x;
    float v = embed[(size_t)tok * E_ + k];
    xh[(size_t)m * E_ + k] = f2bf(v);
}

// ---------------- zero pad columns 1200..1215 of h0sp
__global__ __launch_bounds__(256) void padzero(ushort* __restrict__ h) {
    int idx = blockIdx.x * 256 + threadIdx.x;
    int m = idx >> 4, c = 1200 + (idx & 15);
    h[(size_t)m * KP1 + c] = 0;
}

// ---------------- pack Wih fragment-linear (hi only): [nb(152)][ks(NKS)][512] per dir
// nb = g*38+ub; row u = ub*16 + (lane&15); k = ks*32 + (lane>>4)*8 + e
__global__ __launch_bounds__(512) void pack_wih(const float* __restrict__ Wf,
                                                const float* __restrict__ Wb, int K, int NKS,
                                                ushort* __restrict__ phF,
                                                ushort* __restrict__ phB) {
    int nb = blockIdx.x, ks = blockIdx.y, dz = blockIdx.z;
    const float* W = dz ? Wb : Wf;
    ushort* ph = dz ? phB : phF;
    int tid = threadIdx.x;
    int l = tid >> 3, e = tid & 7;
    int g = nb / 38, ub = nb % 38;
    int u = ub * 16 + (l & 15);
    int k = ks * 32 + (l >> 4) * 8 + e;
    float v = (u < 600 && k < K) ? W[(size_t)(g * 600 + u) * K + k] : 0.f;
    ph[((size_t)nb * NKS + ks) * 512 + tid] = f2bf(v);
}

// ---------------- pack Whh into MFMA fragment-linear layout, hi/lo split
__global__ __launch_bounds__(512) void pack_whh(
    const float* __restrict__ W0f, const float* __restrict__ W0b,
    const float* __restrict__ W1f, const float* __restrict__ W1b,
    ushort* __restrict__ pwh, ushort* __restrict__ pwl) {
    int ub = blockIdx.x, ks = blockIdx.y, ld = blockIdx.z;
    const float* W = (ld == 0) ? W0f : (ld == 1) ? W0b : (ld == 2) ? W1f : W1b;
    int tid = threadIdx.x;
    int l = tid >> 3, e = tid & 7;
    int u = ub * 16 + (l & 15);
    int k = ks * 32 + (l >> 4) * 8 + e;
#pragma unroll
    for (int g = 0; g < 4; ++g) {
        float v = (u < 600 && k < 600) ? W[(size_t)(g * 600 + u) * 600 + k] : 0.f;
        ushort hi = f2bf(v);
        size_t o = ((((size_t)ld * 4 + g) * 38 + ub) * 19 + ks) * 512 + tid;
        pwh[o] = hi;
        pwl[o] = f2bf(v - bf2f(hi));
    }
}

// ---------------- pack biases fragment-linear: [ld(4)][g][ub][lane][4]
__global__ __launch_bounds__(64) void packbias(const float* __restrict__ b0f,
                                               const float* __restrict__ b0b,
                                               const float* __restrict__ b1f,
                                               const float* __restrict__ b1b,
                                               float* __restrict__ bfr) {
    int ub = blockIdx.x, g = blockIdx.y, ld = blockIdx.z;
    const float* b = (ld == 0) ? b0f : (ld == 1) ? b0b : (ld == 2) ? b1f : b1b;
    int lane = threadIdx.x;
    float4 v;
    float* vp = (float*)&v;
#pragma unroll
    for (int r = 0; r < 4; ++r) {
        int u = ub * 16 + (lane >> 4) * 4 + r;
        vp[r] = (u < 600) ? b[g * 600 + u] : 0.f;
    }
    *(float4*)&bfr[((((size_t)ld * 4 + g) * 38 + ub) * 64 + lane) * 4] = v;
}

// ---------------- Wc = W1 @ W2  [1200,4], bc = bm1 @ W2 + bm2  [4]
__global__ void wc_kernel(const float* __restrict__ W1, const float* __restrict__ bm1,
                          const float* __restrict__ W2, const float* __restrict__ bm2,
                          float* __restrict__ Wc, float* __restrict__ bc) {
    int idx = blockIdx.x * 256 + threadIdx.x;
    if (idx < 4800) {
        int k = idx >> 2, l = idx & 3;
        float acc = 0.f;
        for (int j = 0; j < 600; ++j) acc += W1[(size_t)k * 600 + j] * W2[j * 4 + l];
        Wc[idx] = acc;
    }
    if (idx < 4) {
        float acc = bm2[idx];
        for (int j = 0; j < 600; ++j) acc += bm1[j] * W2[j * 4 + idx];
        bc[idx] = acc;
    }
}

// ---------------- cooperative persistent recurrence WITH FUSED INPUT PROJECTION.
// 76 blocks x 256 threads. Per step: x-part (h-independent, fills sync bubble)
// -> grid.sync -> recurrent part (Whh from LDS, 3-term hi/lo) -> epilogue.
#define CC_LOADA(SL, KS)                                                         \
    _Pragma("unroll") for (int g = 0; g < 4; ++g) {                              \
        Ah[SL][g] = *(const bf16x8*)&wlds[0][g][(size_t)(KS)*512 + lane * 8];    \
        Al[SL][g] = *(const bf16x8*)&wlds[1][g][(size_t)(KS)*512 + lane * 8];    \
    }
#define CC_LOADB(SL, KS)                                                         \
    {                                                                            \
        Bh[SL] = *(const bf16x8*)(hHb + (size_t)(KS)*32 + fk8);                  \
        Bl[SL] = *(const bf16x8*)(hLb + (size_t)(KS)*32 + fk8);                  \
    }
#define CC_MF3(SA, SB)                                                           \
    _Pragma("unroll") for (int g = 0; g < 4; ++g)                                \
        acc[g] = __builtin_amdgcn_mfma_f32_16x16x32_bf16(Ah[SA][g], Bh[SB], acc[g], 0, 0, 0); \
    _Pragma("unroll") for (int g = 0; g < 4; ++g)                                \
        acc[g] = __builtin_amdgcn_mfma_f32_16x16x32_bf16(Ah[SA][g], Bl[SB], acc[g], 0, 0, 0); \
    _Pragma("unroll") for (int g = 0; g < 4; ++g)                                \
        acc[g] = __builtin_amdgcn_mfma_f32_16x16x32_bf16(Al[SA][g], Bh[SB], acc[g], 0, 0, 0);

__global__ __launch_bounds__(256, 1) void lstm_chunk_coop(
    const ushort* __restrict__ pwh, const ushort* __restrict__ pwl,   // Whh layer base
    const ushort* __restrict__ xApF, const ushort* __restrict__ xApB, // packed Wih per dir
    const ushort* __restrict__ xB, int Kp, int NKS,                   // x operand rows [m][Kp]
    ushort* __restrict__ hTh, ushort* __restrict__ hTl,  // [2 par][2 dir][64][608]
    int Tc, int step0,
    const float* __restrict__ biasFr, int layer,
    float* __restrict__ cQ,
    ushort* __restrict__ h0H,
    float* __restrict__ h1f, float* __restrict__ h1b, int chunkRows) {
    __shared__ ushort wlds[2][4][19 * 512];  // 155,648 B
    __shared__ float hsh[4][16][17];         // 4,352 B -> 160,000 total
    cg::grid_group grid = cg::this_grid();

    int tid = threadIdx.x;
    int lane = tid & 63, nt = tid >> 6;
    int blk = blockIdx.x;
    int dir = (blk >= 38) ? 1 : 0;
    int ub = blk - dir * 38;
    int u16 = ub * 16;
    int frow = lane & 15, rr = lane >> 4, fk8 = rr * 8;

    // ---- stage this block's Whh slice into LDS (once): 1216 uint4 per gate ----
#pragma unroll
    for (int g = 0; g < 4; ++g) {
        const uint4* sH = (const uint4*)(pwh + (size_t)(dir * 4 + g) * GSTR + (size_t)ub * 9728);
        const uint4* sL = (const uint4*)(pwl + (size_t)(dir * 4 + g) * GSTR + (size_t)ub * 9728);
        uint4* dH = (uint4*)&wlds[0][g][0];
        uint4* dL = (uint4*)&wlds[1][g][0];
        for (int i = tid; i < 1216; i += 256) {
            dH[i] = sH[i];
            dL[i] = sL[i];
        }
    }

    const ushort* xApD = dir ? xApB : xApF;
    float4 bf4[4];
#pragma unroll
    for (int g = 0; g < 4; ++g)
        bf4[g] = *(const float4*)(biasFr + ((((size_t)(layer * 2 + dir) * 4 + g) * 38 + ub) * 64 + lane) * 4);

    int slot = (dir * 38 + ub) * 4 + nt;
    float* cslot = cQ + ((size_t)slot * 64 + lane) * 4;
    float4 cvec = *(float4*)cslot;
    float* cvp = (float*)&cvec;
    __syncthreads();

    for (int s = 0; s < Tc; ++s) {
        int astep = step0 + s;
        int tAbs = dir ? (T_ - 1 - astep) : astep;
        int par = astep & 1;

        // ---- x-part: gates += Wih @ x[tAbs]  (independent of h; fills sync bubble)
        f32x4 acc[4] = {};
        {
            const ushort* xBrow = xB + (size_t)(tAbs * 64 + nt * 16 + frow) * Kp + fk8;
            for (int ks = 0; ks < NKS; ++ks) {
                bf16x8 xb = *(const bf16x8*)(xBrow + (size_t)ks * 32);
#pragma unroll
                for (int g = 0; g < 4; ++g) {
                    bf16x8 xa = *(const bf16x8*)(xApD +
                        (((size_t)(g * 38 + ub) * NKS + ks) * 512 + lane * 8));
                    acc[g] = __builtin_amdgcn_mfma_f32_16x16x32_bf16(xa, xb, acc[g], 0, 0, 0);
                }
            }
        }

        // ---- wait for h[astep] published by all blocks (prev iteration) ----
        if (s != 0) grid.sync();

        const ushort* hHb = hTh + (size_t)par * PARS + ((size_t)dir * 64 + nt * 16 + frow) * 608;
        const ushort* hLb = hTl + (size_t)par * PARS + ((size_t)dir * 64 + nt * 16 + frow) * 608;

        bf16x8 Ah[3][4], Al[3][4], Bh[6], Bl[6];
        CC_LOADB(0, 0) CC_LOADB(1, 1) CC_LOADB(2, 2)
        CC_LOADB(3, 3) CC_LOADB(4, 4) CC_LOADB(5, 5)
        CC_LOADA(0, 0) CC_LOADA(1, 1)
#pragma unroll
        for (int ks = 0; ks < 19; ++ks) {
            const int ca = ks % 3, cb = ks % 6;
            if (ks + 2 < 19) {
                const int pa = (ks + 2) % 3;
                CC_LOADA(pa, ks + 2)
            }
            if (ks + 6 < 19) {
                const int pb = (ks + 6) % 6;
                CC_LOADB(pb, ks + 6)
            }
            CC_MF3(ca, cb)
        }

        // ---- epilogue ----
#pragma unroll
        for (int r = 0; r < 4; ++r) {
            int u = u16 + rr * 4 + r;
            bool valid = (u < 600);
            float gi, gf, gg, go;
            if (valid) {
                gi = acc[0][r] + ((float*)&bf4[0])[r];
                gf = acc[1][r] + ((float*)&bf4[1])[r];
                gg = acc[2][r] + ((float*)&bf4[2])[r];
                go = acc[3][r] + ((float*)&bf4[3])[r];
            } else {
                gi = gf = gg = go = 0.f;
            }
            float cv = cvp[r];
            float si = 1.f / (1.f + expf(-gi));
            float sf = 1.f / (1.f + expf(-gf));
            float so = 1.f / (1.f + expf(-go));
            float cn = sf * cv + si * tanhf(gg);
            float hn = so * tanhf(cn);
            cvp[r] = cn;
            hsh[nt][frow][rr * 4 + r] = hn;
        }
        __syncthreads();
        {
            int mF = astep * 64, mB = (T_ - 1 - astep) * 64;
            int bl = lane >> 2, q = lane & 3;
            int b = nt * 16 + bl;
            float v0 = hsh[nt][bl][q * 4 + 0], v1 = hsh[nt][bl][q * 4 + 1];
            float v2 = hsh[nt][bl][q * 4 + 2], v3 = hsh[nt][bl][q * 4 + 3];
            ushort h0_ = f2bf(v0), h1_ = f2bf(v1), h2_ = f2bf(v2), h3_ = f2bf(v3);
            ushort4 hv = {h0_, h1_, h2_, h3_};
            ushort4 lv = {f2bf(v0 - bf2f(h0_)), f2bf(v1 - bf2f(h1_)),
                          f2bf(v2 - bf2f(h2_)), f2bf(v3 - bf2f(h3_))};
            size_t ho = (size_t)(par ^ 1) * PARS + ((size_t)dir * 64 + b) * 608 + u16 + q * 4;
            *(ushort4*)&hTh[ho] = hv;
            *(ushort4*)&hTl[ho] = lv;
            if (layer == 0 && (u16 + q * 4 < 600)) {
                size_t so_ = (size_t)((dir ? mB : mF) + b) * KP1 + dir * 600 + u16 + q * 4;
                *(ushort4*)&h0H[so_] = hv;
            }
        }
        if (layer == 1) {
            int oF = s * 64, oB = (Tc - 1 - s) * 64;
            int u_l = lane & 15, br = (lane >> 4) * 4;
            if (u16 + u_l < 600) {
                float4 hv;
                hv.x = hsh[nt][br + 0][u_l];
                hv.y = hsh[nt][br + 1][u_l];
                hv.z = hsh[nt][br + 2][u_l];
                hv.w = hsh[nt][br + 3][u_l];
                float* op = dir ? h1b : h1f;
                *(float4*)&op[(size_t)(u16 + u_l) * chunkRows + (dir ? oB : oF) + nt * 16 + br] = hv;
            }
        }
        __syncthreads();  // hsh reuse next step
    }
    *(float4*)cslot = cvec;
}

// ---------------- emission accumulate for one chunk of one direction
__global__ __launch_bounds__(256) void emis_add(const float* __restrict__ h1C, int cols,
                                                const float* __restrict__ Wc,
                                                const float* __restrict__ bc, int addBias,
                                                float* __restrict__ ys, int t0) {
    int lane = threadIdx.x & 63;
    int l = __builtin_amdgcn_readfirstlane(threadIdx.x >> 6);
    int tl = blockIdx.x;
    float acc = addBias ? bc[l] : 0.f;
    for (int k = 0; k < H_; ++k)
        acc = fmaf(h1C[(size_t)k * cols + tl * 64 + lane], Wc[k * 4 + l], acc);
    int t = t0 + tl, b = lane;
    ys[((size_t)b * T_ + t) * 4 + l] += acc;
}

// ---------------- CRF log-likelihood per batch
__global__ void crf_fwd(const float* __restrict__ ys, const int* __restrict__ ls,
                        const float* __restrict__ trans, const float* __restrict__ startT,
                        const float* __restrict__ endT, float* __restrict__ llb) {
    int b = blockIdx.x;
    int lane = threadIdx.x;
    float acc = 0.f;
    for (int t = lane; t < T_; t += 64) {
        int tg = ls[b * T_ + t];
        acc += ys[((size_t)b * T_ + t) * 4 + tg];
        if (t > 0) acc += trans[ls[b * T_ + t - 1] * 4 + tg];
    }
    for (int off = 32; off; off >>= 1) acc += __shfl_down(acc, off);
    float num = 0.f;
    if (lane == 0) num = startT[ls[b * T_]] + acc + endT[ls[b * T_ + T_ - 1]];

    float a = -1e30f;
    if (lane < 4) a = startT[lane] + ys[((size_t)b * T_) * 4 + lane];
    for (int t = 1; t < T_; ++t) {
        float a0 = __shfl(a, 0), a1 = __shfl(a, 1), a2 = __shfl(a, 2), a3 = __shfl(a, 3);
        if (lane < 4) {
            float v0 = a0 + trans[0 * 4 + lane];
            float v1 = a1 + trans[1 * 4 + lane];
            float v2 = a2 + trans[2 * 4 + lane];
            float v3 = a3 + trans[3 * 4 + lane];
            float mx = fmaxf(fmaxf(v0, v1), fmaxf(v2, v3));
            float ssum = expf(v0 - mx) + expf(v1 - mx) + expf(v2 - mx) + expf(v3 - mx);
            a = mx + logf(ssum) + ys[((size_t)b * T_ + t) * 4 + lane];
        }
    }
    float a0 = __shfl(a, 0), a1 = __shfl(a, 1), a2 = __shfl(a, 2), a3 = __shfl(a, 3);
    if (lane == 0) {
        float v0 = a0 + endT[0], v1 = a1 + endT[1], v2 = a2 + endT[2], v3 = a3 + endT[3];
        float mx = fmaxf(fmaxf(v0, v1), fmaxf(v2, v3));
        float den = mx + logf(expf(v0 - mx) + expf(v1 - mx) + expf(v2 - mx) + expf(v3 - mx));
        llb[b] = num - den;
    }
}

__global__ void final_loss(const float* __restrict__ llb, float* __restrict__ out) {
    int lane = threadIdx.x;
    float v = llb[lane];
    for (int off = 32; off; off >>= 1) v += __shfl_down(v, off);
    if (lane == 0) out[0] = -v / 64.0f;
}

// ---------------- Viterbi decode (tags written as float at out[1..])
__global__ void viterbi(const float* __restrict__ ys, const float* __restrict__ trans,
                        const float* __restrict__ startT, const float* __restrict__ endT,
                        float* __restrict__ out) {
    __shared__ unsigned char bp[T_ * 4];
    int b = blockIdx.x;
    int lane = threadIdx.x;
    float a = -1e30f;
    if (lane < 4) a = startT[lane] + ys[((size_t)b * T_) * 4 + lane];
    for (int t = 1; t < T_; ++t) {
        float a0 = __shfl(a, 0), a1 = __shfl(a, 1), a2 = __shfl(a, 2), a3 = __shfl(a, 3);
        if (lane < 4) {
            float av[4] = {a0, a1, a2, a3};
            float best = av[0] + trans[lane];
            int bi = 0;
            for (int lp = 1; lp < 4; ++lp) {
                float v = av[lp] + trans[lp * 4 + lane];
                if (v > best) { best = v; bi = lp; }
            }
            bp[t * 4 + lane] = (unsigned char)bi;
            a = best + ys[((size_t)b * T_ + t) * 4 + lane];
        }
    }
    float a0 = __shfl(a, 0), a1 = __shfl(a, 1), a2 = __shfl(a, 2), a3 = __shfl(a, 3);
    if (lane == 0) {
        float v[4] = {a0 + endT[0], a1 + endT[1], a2 + endT[2], a3 + endT[3]};
        int tag = 0;
        float best = v[0];
        for (int l = 1; l < 4; ++l)
            if (v[l] > best) { best = v[l]; tag = l; }
        out[1 + b * T_ + (T_ - 1)] = (float)tag;
        for (int t = T_ - 1; t >= 1; --t) {
            tag = bp[t * 4 + tag];
            out[1 + b * T_ + t - 1] = (float)tag;
        }
    }
}

extern "C" void kernel_launch(void* const* d_in, const int* in_sizes, int n_in,
                              void* d_out, int out_size, void* d_ws, size_t ws_size,
                              hipStream_t stream) {
    const int* us = (const int*)d_in[0];
    const int* ls = (const int*)d_in[1];
    const float* embed = (const float*)d_in[2];
    const float* Wih0f = (const float*)d_in[3];
    const float* Whh0f = (const float*)d_in[4];
    const float* b0f   = (const float*)d_in[5];
    const float* Wih0b = (const float*)d_in[6];
    const float* Whh0b = (const float*)d_in[7];
    const float* b0b   = (const float*)d_in[8];
    const float* Wih1f = (const float*)d_in[9];
    const float* Whh1f = (const float*)d_in[10];
    const float* b1f   = (const float*)d_in[11];
    const float* Wih1b = (const float*)d_in[12];
    const float* Whh1b = (const float*)d_in[13];
    const float* b1b   = (const float*)d_in[14];
    const float* W1    = (const float*)d_in[15];
    const float* bm1   = (const float*)d_in[16];
    const float* W2    = (const float*)d_in[17];
    const float* bm2   = (const float*)d_in[18];
    const float* trans = (const float*)d_in[19];
    const float* startT= (const float*)d_in[20];
    const float* endT  = (const float*)d_in[21];
    float* out = (float*)d_out;

    char* p = (char*)d_ws;
    auto alloc = [&](size_t bytes) {
        char* r = p;
        p += (bytes + 255) & ~(size_t)255;
        return r;
    };
    ushort* xspH = (ushort*)alloc((size_t)MTOT * E_ * 2);       // 16.8 MB
    ushort* h0spH = (ushort*)alloc((size_t)MTOT * KP1 * 2);     // 79.7 MB
    ushort* pw0hf = (ushort*)alloc((size_t)152 * 8 * 512 * 2);
    ushort* pw0hb = (ushort*)alloc((size_t)152 * 8 * 512 * 2);
    ushort* pw1hf = (ushort*)alloc((size_t)152 * 38 * 512 * 2);
    ushort* pw1hb = (ushort*)alloc((size_t)152 * 38 * 512 * 2);
    ushort* pwh = (ushort*)alloc((size_t)16 * GSTR * 2);
    ushort* pwl = (ushort*)alloc((size_t)16 * GSTR * 2);
    ushort* hTh = (ushort*)alloc((size_t)2 * PARS * 2);  // [par][dir][b][k]
    ushort* hTl = (ushort*)alloc((size_t)2 * PARS * 2);
    float* cQ  = (float*)alloc((size_t)304 * 64 * 4 * 4);
    float* biasFr = (float*)alloc((size_t)4 * 4 * 38 * 64 * 4 * 4);
    float* Wc  = (float*)alloc(4800 * 4);
    float* bc  = (float*)alloc(4 * 4);
    float* ysb = (float*)alloc((size_t)B_ * T_ * 4 * 4);
    float* llb = (float*)alloc(64 * 4);

    size_t used = (size_t)(p - (char*)d_ws);
    // per-Tc bytes: only h1 chunks now (pre buffers eliminated by fusion)
    size_t perTc = (size_t)2 * H_ * 64 * 4;
    int Tc = 512;
    while (Tc > 8 && used + (size_t)Tc * perTc + 4096 > ws_size) Tc >>= 1;
    float* h1fC = (float*)alloc((size_t)H_ * Tc * 64 * 4);
    float* h1bC = (float*)alloc((size_t)H_ * Tc * 64 * 4);
    int nc = T_ / Tc;
    int chunkRows = Tc * 64;

    xsplit<<<MTOT, 256, 0, stream>>>(us, embed, xspH);
    pack_wih<<<dim3(152, 8, 2), 512, 0, stream>>>(Wih0f, Wih0b, E_, 8, pw0hf, pw0hb);
    pack_wih<<<dim3(152, 38, 2), 512, 0, stream>>>(Wih1f, Wih1b, 1200, 38, pw1hf, pw1hb);
    pack_whh<<<dim3(38, 19, 4), 512, 0, stream>>>(Whh0f, Whh0b, Whh1f, Whh1b, pwh, pwl);
    packbias<<<dim3(38, 4, 4), 64, 0, stream>>>(b0f, b0b, b1f, b1b, biasFr);
    padzero<<<(MTOT * 16) / 256, 256, 0, stream>>>(h0spH);
    wc_kernel<<<19, 256, 0, stream>>>(W1, bm1, W2, bm2, Wc, bc);
    zero_kernel<<<(B_ * T_ * 4 + 255) / 256, 256, 0, stream>>>(ysb, B_ * T_ * 4);

    for (int layer = 0; layer < 2; ++layer) {
        int Kp = layer ? KP1 : E_;
        int NKS = Kp / 32;
        const ushort* xB = layer ? h0spH : xspH;
        const ushort* xApF = layer ? pw1hf : pw0hf;
        const ushort* xApB = layer ? pw1hb : pw0hb;
        const ushort* pwhL = pwh + (size_t)layer * 8 * GSTR;
        const ushort* pwlL = pwl + (size_t)layer * 8 * GSTR;

        zero_kernel<<<(PARS + 255) / 256, 256, 0, stream>>>((float*)hTh, PARS);
        zero_kernel<<<(PARS + 255) / 256, 256, 0, stream>>>((float*)hTl, PARS);
        zero_kernel<<<(304 * 64 * 4 + 255) / 256, 256, 0, stream>>>(cQ, 304 * 64 * 4);

        for (int c = 0; c < nc; ++c) {
            int step0 = c * Tc;
            {
                const ushort* a0 = pwhL; const ushort* a1 = pwlL;
                const ushort* a2 = xApF; const ushort* a3 = xApB;
                const ushort* a4 = xB; int a5 = Kp; int a6 = NKS;
                ushort* a7 = hTh; ushort* a8 = hTl;
                int a9 = Tc; int a10 = step0;
                const float* a11 = biasFr; int a12 = layer;
                float* a13 = cQ;
                ushort* a14 = h0spH;
                float* a15 = h1fC; float* a16 = h1bC;
                int a17 = chunkRows;
                void* args[18] = {&a0, &a1, &a2, &a3, &a4, &a5, &a6, &a7, &a8,
                                  &a9, &a10, &a11, &a12, &a13, &a14, &a15, &a16, &a17};
                hipLaunchCooperativeKernel((void*)lstm_chunk_coop, dim3(76), dim3(256),
                                           args, 0, stream);
            }
            if (layer == 1) {
                emis_add<<<Tc, 256, 0, stream>>>(h1fC, chunkRows, Wc, bc, 1, ysb, c * Tc);
                emis_add<<<Tc, 256, 0, stream>>>(h1bC, chunkRows, Wc + 600 * 4, bc, 0, ysb,
                                                 T_ - (c + 1) * Tc);
            }
        }
    }

    crf_fwd<<<B_, 64, 0, stream>>>(ysb, ls, trans, startT, endT, llb);
    final_loss<<<1, 64, 0, stream>>>(llb, out);
    viterbi<<<B_, 64, 0, stream>>>(ysb, trans, startT, endT, out);
}

// Round 15
// 18970.648 us; speedup vs baseline: 1.1516x; 1.1516x over previous
//
#include <hip/hip_runtime.h>
#include <hip/hip_bf16.h>
#include <hip/hip_cooperative_groups.h>
#include <math.h>

namespace cg = cooperative_groups;

#define T_ 512
#define B_ 64
#define E_ 256
#define H_ 600
#define G4 2400    // 4*H
#define MTOT 32768 // T*B
#define NP 2432    // padded gate rows = 4 gates x 608
#define KP1 1216   // padded K for layer 1 (38*32)
#define GSTR (38 * 19 * 512)  // per-gate packed Whh stride (ushorts)
#define PARS (2 * 64 * 608)   // ushorts per h-parity buffer

typedef __attribute__((ext_vector_type(8))) short bf16x8;
typedef __attribute__((ext_vector_type(4))) float f32x4;

static __device__ __forceinline__ ushort f2bf(float x) {
    unsigned u = __builtin_bit_cast(unsigned, x);
    unsigned r = (u + 0x7FFFu + ((u >> 16) & 1u)) >> 16;
    return (ushort)r;
}
static __device__ __forceinline__ float bf2f(ushort h) {
    unsigned u = ((unsigned)h) << 16;
    return __builtin_bit_cast(float, u);
}

// ---------------- generic zero
__global__ __launch_bounds__(256) void zero_kernel(float* __restrict__ p, int n) {
    int i = blockIdx.x * 256 + threadIdx.x;
    if (i < n) p[i] = 0.f;
}

// ---------------- embedding gather + bf16: xh[m][k], m = t*64+b
__global__ __launch_bounds__(256) void xsplit(const int* __restrict__ us,
                                              const float* __restrict__ embed,
                                              ushort* __restrict__ xh) {
    int m = blockIdx.x;
    int t = m >> 6, b = m & 63;
    int tok = us[b * T_ + t];
    int k = threadIdx.x;
    float v = embed[(size_t)tok * E_ + k];
    xh[(size_t)m * E_ + k] = f2bf(v);
}

// ---------------- zero pad columns 1200..1215 of h0sp
__global__ __launch_bounds__(256) void padzero(ushort* __restrict__ h) {
    int idx = blockIdx.x * 256 + threadIdx.x;
    int m = idx >> 4, c = 1200 + (idx & 15);
    h[(size_t)m * KP1 + c] = 0;
}

// ---------------- pack Wih fragment-linear (hi only): [nb(152)][ks(NKS)][512] per dir
__global__ __launch_bounds__(512) void pack_wih(const float* __restrict__ Wf,
                                                const float* __restrict__ Wb, int K, int NKS,
                                                ushort* __restrict__ phF,
                                                ushort* __restrict__ phB) {
    int nb = blockIdx.x, ks = blockIdx.y, dz = blockIdx.z;
    const float* W = dz ? Wb : Wf;
    ushort* ph = dz ? phB : phF;
    int tid = threadIdx.x;
    int l = tid >> 3, e = tid & 7;
    int g = nb / 38, ub = nb % 38;
    int u = ub * 16 + (l & 15);
    int k = ks * 32 + (l >> 4) * 8 + e;
    float v = (u < 600 && k < K) ? W[(size_t)(g * 600 + u) * K + k] : 0.f;
    ph[((size_t)nb * NKS + ks) * 512 + tid] = f2bf(v);
}

// ---------------- pack Whh into MFMA fragment-linear layout, hi/lo split
__global__ __launch_bounds__(512) void pack_whh(
    const float* __restrict__ W0f, const float* __restrict__ W0b,
    const float* __restrict__ W1f, const float* __restrict__ W1b,
    ushort* __restrict__ pwh, ushort* __restrict__ pwl) {
    int ub = blockIdx.x, ks = blockIdx.y, ld = blockIdx.z;
    const float* W = (ld == 0) ? W0f : (ld == 1) ? W0b : (ld == 2) ? W1f : W1b;
    int tid = threadIdx.x;
    int l = tid >> 3, e = tid & 7;
    int u = ub * 16 + (l & 15);
    int k = ks * 32 + (l >> 4) * 8 + e;
#pragma unroll
    for (int g = 0; g < 4; ++g) {
        float v = (u < 600 && k < 600) ? W[(size_t)(g * 600 + u) * 600 + k] : 0.f;
        ushort hi = f2bf(v);
        size_t o = ((((size_t)ld * 4 + g) * 38 + ub) * 19 + ks) * 512 + tid;
        pwh[o] = hi;
        pwl[o] = f2bf(v - bf2f(hi));
    }
}

// ---------------- pack biases fragment-linear: [ld(4)][g][ub][lane][4]
__global__ __launch_bounds__(64) void packbias(const float* __restrict__ b0f,
                                               const float* __restrict__ b0b,
                                               const float* __restrict__ b1f,
                                               const float* __restrict__ b1b,
                                               float* __restrict__ bfr) {
    int ub = blockIdx.x, g = blockIdx.y, ld = blockIdx.z;
    const float* b = (ld == 0) ? b0f : (ld == 1) ? b0b : (ld == 2) ? b1f : b1b;
    int lane = threadIdx.x;
    float4 v;
    float* vp = (float*)&v;
#pragma unroll
    for (int r = 0; r < 4; ++r) {
        int u = ub * 16 + (lane >> 4) * 4 + r;
        vp[r] = (u < 600) ? b[g * 600 + u] : 0.f;
    }
    *(float4*)&bfr[((((size_t)ld * 4 + g) * 38 + ub) * 64 + lane) * 4] = v;
}

// ---------------- Wc = W1 @ W2  [1200,4], bc = bm1 @ W2 + bm2  [4]
__global__ void wc_kernel(const float* __restrict__ W1, const float* __restrict__ bm1,
                          const float* __restrict__ W2, const float* __restrict__ bm2,
                          float* __restrict__ Wc, float* __restrict__ bc) {
    int idx = blockIdx.x * 256 + threadIdx.x;
    if (idx < 4800) {
        int k = idx >> 2, l = idx & 3;
        float acc = 0.f;
        for (int j = 0; j < 600; ++j) acc += W1[(size_t)k * 600 + j] * W2[j * 4 + l];
        Wc[idx] = acc;
    }
    if (idx < 4) {
        float acc = bm2[idx];
        for (int j = 0; j < 600; ++j) acc += bm1[j] * W2[j * 4 + idx];
        bc[idx] = acc;
    }
}

// ---------------- bf16 MFMA GEMM (single term), A direct from packed global, B dbuf LDS.
// Output fragment-linear BF16: pre[t][g][ub][nt][lane][4]
#define LOADAG(Ah, KS)                                                           \
    _Pragma("unroll") for (int i = 0; i < 4; ++i) {                              \
        size_t o = ((size_t)(wn16 + i) * NKS + (KS)) * 512 + lane * 8;           \
        Ah[i] = *(const bf16x8*)(Aph + o);                                       \
    }
#define READB(BUF)                                                               \
    _Pragma("unroll") for (int j = 0; j < 4; ++j) {                              \
        bh[j] = *(const bf16x8*)&BsH[BUF][wm + j * 16 + fr][kb8];                \
    }
#define MFALL(Ah)                                                                \
    _Pragma("unroll") for (int i = 0; i < 4; ++i)                                \
        _Pragma("unroll") for (int j = 0; j < 4; ++j)                            \
            acc[i][j] = __builtin_amdgcn_mfma_f32_16x16x32_bf16(Ah[i], bh[j], acc[i][j], 0, 0, 0);

__global__ __launch_bounds__(256) void gemm_mfma(
    const ushort* __restrict__ AphF, const ushort* __restrict__ AphB,
    const ushort* __restrict__ actH,
    int Kp, int NKS, int m_offF, int m_offB,
    ushort* __restrict__ preF, ushort* __restrict__ preB) {
    __shared__ __align__(16) ushort BsH[2][128][40];
    const ushort* Aph = blockIdx.z ? AphB : AphF;
    ushort* preX = blockIdx.z ? preB : preF;
    int m_off = blockIdx.z ? m_offB : m_offF;
    int n0 = blockIdx.x * 128, m0 = blockIdx.y * 128;
    int tid = threadIdx.x, lane = tid & 63, w = tid >> 6;
    int wn16 = (n0 >> 4) + (w >> 1) * 4;
    int wm = (w & 1) * 64;
    int fr = lane & 15, kb8 = (lane >> 4) * 8;
    int srow = tid >> 1, skg = (tid & 1) * 16;
    const ushort* bHrow = actH + (size_t)(m_off + m0 + srow) * Kp + skg;

    uint4 rh0 = *(const uint4*)bHrow, rh1 = *(const uint4*)(bHrow + 8);

    bf16x8 a0h[4], a1h[4], bh[4];
    LOADAG(a0h, 0)

    f32x4 acc[4][4] = {};

    for (int ks = 0; ks < NKS; ks += 2) {
        *(uint4*)&BsH[0][srow][skg] = rh0;
        *(uint4*)&BsH[0][srow][skg + 8] = rh1;
        {
            const ushort* bh_ = bHrow + (ks + 1) * 32;
            rh0 = *(const uint4*)bh_; rh1 = *(const uint4*)(bh_ + 8);
        }
        LOADAG(a1h, ks + 1)
        __syncthreads();
        READB(0)
        MFALL(a0h)
        __syncthreads();
        *(uint4*)&BsH[1][srow][skg] = rh0;
        *(uint4*)&BsH[1][srow][skg + 8] = rh1;
        {
            int ksn = (ks + 2 < NKS) ? ks + 2 : 0;
            const ushort* bh_ = bHrow + ksn * 32;
            rh0 = *(const uint4*)bh_; rh1 = *(const uint4*)(bh_ + 8);
            LOADAG(a0h, ksn)
        }
        __syncthreads();
        READB(1)
        MFALL(a1h)
        __syncthreads();
    }

#pragma unroll
    for (int i = 0; i < 4; ++i) {
        int n16 = wn16 + i;
        int g = n16 / 38, ub = n16 - g * 38;
#pragma unroll
        for (int j = 0; j < 4; ++j) {
            int mloc = m0 + wm + j * 16;
            int tl = mloc >> 6, ntg = (mloc >> 4) & 3;
            ushort* dst = preX + (((((size_t)tl * 4 + g) * 38 + ub) * 4 + ntg) * 64 + lane) * 4;
            ushort4 o;
            o.x = f2bf(acc[i][j][0]);
            o.y = f2bf(acc[i][j][1]);
            o.z = f2bf(acc[i][j][2]);
            o.w = f2bf(acc[i][j][3]);
            *(ushort4*)dst = o;
        }
    }
}

// ---------------- cooperative persistent recurrence (r13 structure, bf16 pre/h1).
#define CC_LOADA(SL, KS)                                                         \
    _Pragma("unroll") for (int g = 0; g < 4; ++g) {                              \
        Ah[SL][g] = *(const bf16x8*)&wlds[0][g][(size_t)(KS)*512 + lane * 8];    \
        Al[SL][g] = *(const bf16x8*)&wlds[1][g][(size_t)(KS)*512 + lane * 8];    \
    }
#define CC_LOADB(SL, KS)                                                         \
    {                                                                            \
        Bh[SL] = *(const bf16x8*)(hHb + (size_t)(KS)*32 + fk8);                  \
        Bl[SL] = *(const bf16x8*)(hLb + (size_t)(KS)*32 + fk8);                  \
    }
#define CC_MF3(SA, SB)                                                           \
    _Pragma("unroll") for (int g = 0; g < 4; ++g)                                \
        acc[g] = __builtin_amdgcn_mfma_f32_16x16x32_bf16(Ah[SA][g], Bh[SB], acc[g], 0, 0, 0); \
    _Pragma("unroll") for (int g = 0; g < 4; ++g)                                \
        acc[g] = __builtin_amdgcn_mfma_f32_16x16x32_bf16(Ah[SA][g], Bl[SB], acc[g], 0, 0, 0); \
    _Pragma("unroll") for (int g = 0; g < 4; ++g)                                \
        acc[g] = __builtin_amdgcn_mfma_f32_16x16x32_bf16(Al[SA][g], Bh[SB], acc[g], 0, 0, 0);

__global__ __launch_bounds__(256, 1) void lstm_chunk_coop(
    const ushort* __restrict__ pwh, const ushort* __restrict__ pwl,  // layer base
    ushort* __restrict__ hTh, ushort* __restrict__ hTl,  // [2 par][2 dir][64][608]
    const ushort* __restrict__ preF2, const ushort* __restrict__ preB2,  // bf16 frag-linear
    int Tc, int step0,
    const float* __restrict__ biasFr, int layer,
    float* __restrict__ cQ,
    ushort* __restrict__ h0H,
    ushort* __restrict__ h1f, ushort* __restrict__ h1b, int chunkRows) {
    __shared__ ushort wlds[2][4][19 * 512];  // 155,648 B
    __shared__ float hsh[4][16][17];         // 4,352 B -> 160,000 total
    cg::grid_group grid = cg::this_grid();

    int tid = threadIdx.x;
    int lane = tid & 63, nt = tid >> 6;
    int blk = blockIdx.x;
    int dir = (blk >= 38) ? 1 : 0;
    int ub = blk - dir * 38;
    int u16 = ub * 16;
    int frow = lane & 15, rr = lane >> 4, fk8 = rr * 8;

    // ---- stage Whh slice into LDS: 1216 uint4 per gate per (hi/lo) ----
#pragma unroll
    for (int g = 0; g < 4; ++g) {
        const uint4* sH = (const uint4*)(pwh + (size_t)(dir * 4 + g) * GSTR + (size_t)ub * 9728);
        const uint4* sL = (const uint4*)(pwl + (size_t)(dir * 4 + g) * GSTR + (size_t)ub * 9728);
        uint4* dH = (uint4*)&wlds[0][g][0];
        uint4* dL = (uint4*)&wlds[1][g][0];
        for (int i = tid; i < 1216; i += 256) {
            dH[i] = sH[i];
            dL[i] = sL[i];
        }
    }

    const ushort* preX = dir ? preB2 : preF2;
    float4 bf4[4];
#pragma unroll
    for (int g = 0; g < 4; ++g)
        bf4[g] = *(const float4*)(biasFr + ((((size_t)(layer * 2 + dir) * 4 + g) * 38 + ub) * 64 + lane) * 4);

    int slot = (dir * 38 + ub) * 4 + nt;
    float* cslot = cQ + ((size_t)slot * 64 + lane) * 4;
    float4 cvec = *(float4*)cslot;
    float* cvp = (float*)&cvec;
    __syncthreads();

    for (int s = 0; s < Tc; ++s) {
        int par = (step0 + s) & 1;
        const ushort* hHb = hTh + (size_t)par * PARS + ((size_t)dir * 64 + nt * 16 + frow) * 608;
        const ushort* hLb = hTl + (size_t)par * PARS + ((size_t)dir * 64 + nt * 16 + frow) * 608;
        int t = dir ? (Tc - 1 - s) : s;

        float pgv[4][4];
#pragma unroll
        for (int g = 0; g < 4; ++g) {
            ushort4 pu = *(const ushort4*)(preX +
                (((((size_t)t * 4 + g) * 38 + ub) * 4 + nt) * 64 + lane) * 4);
            pgv[g][0] = bf2f(pu.x);
            pgv[g][1] = bf2f(pu.y);
            pgv[g][2] = bf2f(pu.z);
            pgv[g][3] = bf2f(pu.w);
        }

        f32x4 acc[4] = {};
        bf16x8 Ah[3][4], Al[3][4], Bh[6], Bl[6];
        CC_LOADB(0, 0) CC_LOADB(1, 1) CC_LOADB(2, 2)
        CC_LOADB(3, 3) CC_LOADB(4, 4) CC_LOADB(5, 5)
        CC_LOADA(0, 0) CC_LOADA(1, 1)
#pragma unroll
        for (int ks = 0; ks < 19; ++ks) {
            const int ca = ks % 3, cb = ks % 6;
            if (ks + 2 < 19) {
                const int pa = (ks + 2) % 3;
                CC_LOADA(pa, ks + 2)
            }
            if (ks + 6 < 19) {
                const int pb = (ks + 6) % 6;
                CC_LOADB(pb, ks + 6)
            }
            CC_MF3(ca, cb)
        }

        // ---- epilogue ----
#pragma unroll
        for (int r = 0; r < 4; ++r) {
            int u = u16 + rr * 4 + r;
            bool valid = (u < 600);
            float gi, gf, gg, go;
            if (valid) {
                gi = acc[0][r] + pgv[0][r] + ((float*)&bf4[0])[r];
                gf = acc[1][r] + pgv[1][r] + ((float*)&bf4[1])[r];
                gg = acc[2][r] + pgv[2][r] + ((float*)&bf4[2])[r];
                go = acc[3][r] + pgv[3][r] + ((float*)&bf4[3])[r];
            } else {
                gi = gf = gg = go = 0.f;
            }
            float cv = cvp[r];
            float si = 1.f / (1.f + expf(-gi));
            float sf = 1.f / (1.f + expf(-gf));
            float so = 1.f / (1.f + expf(-go));
            float cn = sf * cv + si * tanhf(gg);
            float hn = so * tanhf(cn);
            cvp[r] = cn;
            hsh[nt][frow][rr * 4 + r] = hn;
        }
        __syncthreads();
        {
            int step = step0 + s;
            int mF = step * 64, mB = (T_ - 1 - step) * 64;
            int bl = lane >> 2, q = lane & 3;
            int b = nt * 16 + bl;
            float v0 = hsh[nt][bl][q * 4 + 0], v1 = hsh[nt][bl][q * 4 + 1];
            float v2 = hsh[nt][bl][q * 4 + 2], v3 = hsh[nt][bl][q * 4 + 3];
            ushort h0_ = f2bf(v0), h1_ = f2bf(v1), h2_ = f2bf(v2), h3_ = f2bf(v3);
            ushort4 hv = {h0_, h1_, h2_, h3_};
            ushort4 lv = {f2bf(v0 - bf2f(h0_)), f2bf(v1 - bf2f(h1_)),
                          f2bf(v2 - bf2f(h2_)), f2bf(v3 - bf2f(h3_))};
            size_t ho = (size_t)(par ^ 1) * PARS + ((size_t)dir * 64 + b) * 608 + u16 + q * 4;
            *(ushort4*)&hTh[ho] = hv;
            *(ushort4*)&hTl[ho] = lv;
            if (layer == 0 && (u16 + q * 4 < 600)) {
                size_t so_ = (size_t)((dir ? mB : mF) + b) * KP1 + dir * 600 + u16 + q * 4;
                *(ushort4*)&h0H[so_] = hv;
            }
        }
        if (layer == 1) {
            int oF = s * 64, oB = (Tc - 1 - s) * 64;
            int u_l = lane & 15, br = (lane >> 4) * 4;
            if (u16 + u_l < 600) {
                ushort4 hv4;
                hv4.x = f2bf(hsh[nt][br + 0][u_l]);
                hv4.y = f2bf(hsh[nt][br + 1][u_l]);
                hv4.z = f2bf(hsh[nt][br + 2][u_l]);
                hv4.w = f2bf(hsh[nt][br + 3][u_l]);
                ushort* op = dir ? h1b : h1f;
                *(ushort4*)&op[(size_t)(u16 + u_l) * chunkRows + (dir ? oB : oF) + nt * 16 + br] = hv4;
            }
        }
        __syncthreads();  // hsh reuse next step
        if (s != Tc - 1) grid.sync();
    }
    *(float4*)cslot = cvec;
}

// ---------------- emission accumulate for one chunk of one direction (bf16 h1)
__global__ __launch_bounds__(256) void emis_add(const ushort* __restrict__ h1C, int cols,
                                                const float* __restrict__ Wc,
                                                const float* __restrict__ bc, int addBias,
                                                float* __restrict__ ys, int t0) {
    int lane = threadIdx.x & 63;
    int l = __builtin_amdgcn_readfirstlane(threadIdx.x >> 6);
    int tl = blockIdx.x;
    float acc = addBias ? bc[l] : 0.f;
    for (int k = 0; k < H_; ++k)
        acc = fmaf(bf2f(h1C[(size_t)k * cols + tl * 64 + lane]), Wc[k * 4 + l], acc);
    int t = t0 + tl, b = lane;
    ys[((size_t)b * T_ + t) * 4 + l] += acc;
}

// ---------------- CRF log-likelihood per batch
__global__ void crf_fwd(const float* __restrict__ ys, const int* __restrict__ ls,
                        const float* __restrict__ trans, const float* __restrict__ startT,
                        const float* __restrict__ endT, float* __restrict__ llb) {
    int b = blockIdx.x;
    int lane = threadIdx.x;
    float acc = 0.f;
    for (int t = lane; t < T_; t += 64) {
        int tg = ls[b * T_ + t];
        acc += ys[((size_t)b * T_ + t) * 4 + tg];
        if (t > 0) acc += trans[ls[b * T_ + t - 1] * 4 + tg];
    }
    for (int off = 32; off; off >>= 1) acc += __shfl_down(acc, off);
    float num = 0.f;
    if (lane == 0) num = startT[ls[b * T_]] + acc + endT[ls[b * T_ + T_ - 1]];

    float a = -1e30f;
    if (lane < 4) a = startT[lane] + ys[((size_t)b * T_) * 4 + lane];
    for (int t = 1; t < T_; ++t) {
        float a0 = __shfl(a, 0), a1 = __shfl(a, 1), a2 = __shfl(a, 2), a3 = __shfl(a, 3);
        if (lane < 4) {
            float v0 = a0 + trans[0 * 4 + lane];
            float v1 = a1 + trans[1 * 4 + lane];
            float v2 = a2 + trans[2 * 4 + lane];
            float v3 = a3 + trans[3 * 4 + lane];
            float mx = fmaxf(fmaxf(v0, v1), fmaxf(v2, v3));
            float ssum = expf(v0 - mx) + expf(v1 - mx) + expf(v2 - mx) + expf(v3 - mx);
            a = mx + logf(ssum) + ys[((size_t)b * T_ + t) * 4 + lane];
        }
    }
    float a0 = __shfl(a, 0), a1 = __shfl(a, 1), a2 = __shfl(a, 2), a3 = __shfl(a, 3);
    if (lane == 0) {
        float v0 = a0 + endT[0], v1 = a1 + endT[1], v2 = a2 + endT[2], v3 = a3 + endT[3];
        float mx = fmaxf(fmaxf(v0, v1), fmaxf(v2, v3));
        float den = mx + logf(expf(v0 - mx) + expf(v1 - mx) + expf(v2 - mx) + expf(v3 - mx));
        llb[b] = num - den;
    }
}

__global__ void final_loss(const float* __restrict__ llb, float* __restrict__ out) {
    int lane = threadIdx.x;
    float v = llb[lane];
    for (int off = 32; off; off >>= 1) v += __shfl_down(v, off);
    if (lane == 0) out[0] = -v / 64.0f;
}

// ---------------- Viterbi decode (tags written as float at out[1..])
__global__ void viterbi(const float* __restrict__ ys, const float* __restrict__ trans,
                        const float* __restrict__ startT, const float* __restrict__ endT,
                        float* __restrict__ out) {
    __shared__ unsigned char bp[T_ * 4];
    int b = blockIdx.x;
    int lane = threadIdx.x;
    float a = -1e30f;
    if (lane < 4) a = startT[lane] + ys[((size_t)b * T_) * 4 + lane];
    for (int t = 1; t < T_; ++t) {
        float a0 = __shfl(a, 0), a1 = __shfl(a, 1), a2 = __shfl(a, 2), a3 = __shfl(a, 3);
        if (lane < 4) {
            float av[4] = {a0, a1, a2, a3};
            float best = av[0] + trans[lane];
            int bi = 0;
            for (int lp = 1; lp < 4; ++lp) {
                float v = av[lp] + trans[lp * 4 + lane];
                if (v > best) { best = v; bi = lp; }
            }
            bp[t * 4 + lane] = (unsigned char)bi;
            a = best + ys[((size_t)b * T_ + t) * 4 + lane];
        }
    }
    float a0 = __shfl(a, 0), a1 = __shfl(a, 1), a2 = __shfl(a, 2), a3 = __shfl(a, 3);
    if (lane == 0) {
        float v[4] = {a0 + endT[0], a1 + endT[1], a2 + endT[2], a3 + endT[3]};
        int tag = 0;
        float best = v[0];
        for (int l = 1; l < 4; ++l)
            if (v[l] > best) { best = v[l]; tag = l; }
        out[1 + b * T_ + (T_ - 1)] = (float)tag;
        for (int t = T_ - 1; t >= 1; --t) {
            tag = bp[t * 4 + tag];
            out[1 + b * T_ + t - 1] = (float)tag;
        }
    }
}

extern "C" void kernel_launch(void* const* d_in, const int* in_sizes, int n_in,
                              void* d_out, int out_size, void* d_ws, size_t ws_size,
                              hipStream_t stream) {
    const int* us = (const int*)d_in[0];
    const int* ls = (const int*)d_in[1];
    const float* embed = (const float*)d_in[2];
    const float* Wih0f = (const float*)d_in[3];
    const float* Whh0f = (const float*)d_in[4];
    const float* b0f   = (const float*)d_in[5];
    const float* Wih0b = (const float*)d_in[6];
    const float* Whh0b = (const float*)d_in[7];
    const float* b0b   = (const float*)d_in[8];
    const float* Wih1f = (const float*)d_in[9];
    const float* Whh1f = (const float*)d_in[10];
    const float* b1f   = (const float*)d_in[11];
    const float* Wih1b = (const float*)d_in[12];
    const float* Whh1b = (const float*)d_in[13];
    const float* b1b   = (const float*)d_in[14];
    const float* W1    = (const float*)d_in[15];
    const float* bm1   = (const float*)d_in[16];
    const float* W2    = (const float*)d_in[17];
    const float* bm2   = (const float*)d_in[18];
    const float* trans = (const float*)d_in[19];
    const float* startT= (const float*)d_in[20];
    const float* endT  = (const float*)d_in[21];
    float* out = (float*)d_out;

    char* p = (char*)d_ws;
    auto alloc = [&](size_t bytes) {
        char* r = p;
        p += (bytes + 255) & ~(size_t)255;
        return r;
    };
    ushort* xspH = (ushort*)alloc((size_t)MTOT * E_ * 2);       // 16.8 MB
    ushort* h0spH = (ushort*)alloc((size_t)MTOT * KP1 * 2);     // 79.7 MB
    ushort* pw0hf = (ushort*)alloc((size_t)152 * 8 * 512 * 2);
    ushort* pw0hb = (ushort*)alloc((size_t)152 * 8 * 512 * 2);
    ushort* pw1hf = (ushort*)alloc((size_t)152 * 38 * 512 * 2);
    ushort* pw1hb = (ushort*)alloc((size_t)152 * 38 * 512 * 2);
    ushort* pwh = (ushort*)alloc((size_t)16 * GSTR * 2);
    ushort* pwl = (ushort*)alloc((size_t)16 * GSTR * 2);
    ushort* hTh = (ushort*)alloc((size_t)2 * PARS * 2);  // [par][dir][b][k]
    ushort* hTl = (ushort*)alloc((size_t)2 * PARS * 2);
    float* cQ  = (float*)alloc((size_t)304 * 64 * 4 * 4);
    float* biasFr = (float*)alloc((size_t)4 * 4 * 38 * 64 * 4 * 4);
    float* Wc  = (float*)alloc(4800 * 4);
    float* bc  = (float*)alloc(4 * 4);
    float* ysb = (float*)alloc((size_t)B_ * T_ * 4 * 4);
    float* llb = (float*)alloc(64 * 4);

    size_t used = (size_t)(p - (char*)d_ws);
    // per-Tc bytes: bf16 pre (2 dirs x 2432*64*2) + bf16 h1 chunks (2 x 600*64*2)
    size_t perTc = (size_t)2 * 2432 * 64 * 2 + (size_t)2 * H_ * 64 * 2;
    int Tc = 512;
    while (Tc > 8 && used + (size_t)Tc * perTc + 4096 > ws_size) Tc >>= 1;
    ushort* preF = (ushort*)alloc((size_t)Tc * 2432 * 64 * 2);
    ushort* preB = (ushort*)alloc((size_t)Tc * 2432 * 64 * 2);
    ushort* h1fC = (ushort*)alloc((size_t)H_ * Tc * 64 * 2);
    ushort* h1bC = (ushort*)alloc((size_t)H_ * Tc * 64 * 2);
    int nc = T_ / Tc;
    int chunkRows = Tc * 64;

    xsplit<<<MTOT, 256, 0, stream>>>(us, embed, xspH);
    pack_wih<<<dim3(152, 8, 2), 512, 0, stream>>>(Wih0f, Wih0b, E_, 8, pw0hf, pw0hb);
    pack_wih<<<dim3(152, 38, 2), 512, 0, stream>>>(Wih1f, Wih1b, 1200, 38, pw1hf, pw1hb);
    pack_whh<<<dim3(38, 19, 4), 512, 0, stream>>>(Whh0f, Whh0b, Whh1f, Whh1b, pwh, pwl);
    packbias<<<dim3(38, 4, 4), 64, 0, stream>>>(b0f, b0b, b1f, b1b, biasFr);
    padzero<<<(MTOT * 16) / 256, 256, 0, stream>>>(h0spH);
    wc_kernel<<<19, 256, 0, stream>>>(W1, bm1, W2, bm2, Wc, bc);
    zero_kernel<<<(B_ * T_ * 4 + 255) / 256, 256, 0, stream>>>(ysb, B_ * T_ * 4);

    for (int layer = 0; layer < 2; ++layer) {
        int Kp = layer ? KP1 : E_;
        int NKS = Kp / 32;
        const ushort* aH = layer ? h0spH : xspH;
        const ushort* AphF = layer ? pw1hf : pw0hf;
        const ushort* AphB = layer ? pw1hb : pw0hb;
        const ushort* pwhL = pwh + (size_t)layer * 8 * GSTR;
        const ushort* pwlL = pwl + (size_t)layer * 8 * GSTR;

        zero_kernel<<<(PARS + 255) / 256, 256, 0, stream>>>((float*)hTh, PARS);
        zero_kernel<<<(PARS + 255) / 256, 256, 0, stream>>>((float*)hTl, PARS);
        zero_kernel<<<(304 * 64 * 4 + 255) / 256, 256, 0, stream>>>(cQ, 304 * 64 * 4);

        for (int c = 0; c < nc; ++c) {
            int moffF = c * Tc * 64;
            int moffB = (T_ - (c + 1) * Tc) * 64;
            dim3 gg(NP / 128, chunkRows / 128, 2);
            gemm_mfma<<<gg, 256, 0, stream>>>(AphF, AphB, aH, Kp, NKS, moffF, moffB,
                                              preF, preB);
            {
                int step0 = c * Tc;
                const ushort* a0 = pwhL; const ushort* a1 = pwlL;
                ushort* a2 = hTh; ushort* a3 = hTl;
                const ushort* a4 = preF; const ushort* a5 = preB;
                int a6 = Tc; int a7 = step0;
                const float* a8 = biasFr; int a9 = layer;
                float* a10 = cQ;
                ushort* a11 = h0spH;
                ushort* a12 = h1fC; ushort* a13 = h1bC;
                int a14 = chunkRows;
                void* args[15] = {&a0, &a1, &a2, &a3, &a4, &a5, &a6, &a7,
                                  &a8, &a9, &a10, &a11, &a12, &a13, &a14};
                hipLaunchCooperativeKernel((void*)lstm_chunk_coop, dim3(76), dim3(256),
                                           args, 0, stream);
            }
            if (layer == 1) {
                emis_add<<<Tc, 256, 0, stream>>>(h1fC, chunkRows, Wc, bc, 1, ysb, c * Tc);
                emis_add<<<Tc, 256, 0, stream>>>(h1bC, chunkRows, Wc + 600 * 4, bc, 0, ysb,
                                                 T_ - (c + 1) * Tc);
            }
        }
    }

    crf_fwd<<<B_, 64, 0, stream>>>(ysb, ls, trans, startT, endT, llb);
    final_loss<<<1, 64, 0, stream>>>(llb, out);
    viterbi<<<B_, 64, 0, stream>>>(ysb, trans, startT, endT, out);
}

// Round 16
// 14025.809 us; speedup vs baseline: 1.5577x; 1.3526x over previous
//
#include <hip/hip_runtime.h>
#include <hip/hip_bf16.h>
#include <math.h>

#define T_ 512
#define B_ 64
#define E_ 256
#define H_ 600
#define G4 2400    // 4*H
#define MTOT 32768 // T*B
#define NP 2432    // padded gate rows = 4 gates x 608
#define KP1 1216   // padded K for layer 1 (38*32)
#define GSTR (38 * 19 * 512)  // per-gate packed Whh stride (ushorts)
#define PARS (2 * 64 * 608)   // ushorts per h-parity buffer

typedef __attribute__((ext_vector_type(8))) short bf16x8;
typedef __attribute__((ext_vector_type(4))) float f32x4;

static __device__ __forceinline__ ushort f2bf(float x) {
    unsigned u = __builtin_bit_cast(unsigned, x);
    unsigned r = (u + 0x7FFFu + ((u >> 16) & 1u)) >> 16;
    return (ushort)r;
}
static __device__ __forceinline__ float bf2f(ushort h) {
    unsigned u = ((unsigned)h) << 16;
    return __builtin_bit_cast(float, u);
}

// ---------------- generic zero
__global__ __launch_bounds__(256) void zero_kernel(float* __restrict__ p, int n) {
    int i = blockIdx.x * 256 + threadIdx.x;
    if (i < n) p[i] = 0.f;
}

// ---------------- zero three 77824-float arrays in one launch (hT hi/lo + cQ)
__global__ __launch_bounds__(256) void zero3(float* __restrict__ a, float* __restrict__ b,
                                             float* __restrict__ c) {
    int i = blockIdx.x * 256 + threadIdx.x;
    a[i] = 0.f;
    b[i] = 0.f;
    c[i] = 0.f;
}

// ---------------- embedding gather + bf16: xh[m][k], m = t*64+b
__global__ __launch_bounds__(256) void xsplit(const int* __restrict__ us,
                                              const float* __restrict__ embed,
                                              ushort* __restrict__ xh) {
    int m = blockIdx.x;
    int t = m >> 6, b = m & 63;
    int tok = us[b * T_ + t];
    int k = threadIdx.x;
    float v = embed[(size_t)tok * E_ + k];
    xh[(size_t)m * E_ + k] = f2bf(v);
}

// ---------------- zero pad columns 1200..1215 of h0sp
__global__ __launch_bounds__(256) void padzero(ushort* __restrict__ h) {
    int idx = blockIdx.x * 256 + threadIdx.x;
    int m = idx >> 4, c = 1200 + (idx & 15);
    h[(size_t)m * KP1 + c] = 0;
}

// ---------------- pack Wih fragment-linear (hi only): [nb(152)][ks(NKS)][512] per dir
__global__ __launch_bounds__(512) void pack_wih(const float* __restrict__ Wf,
                                                const float* __restrict__ Wb, int K, int NKS,
                                                ushort* __restrict__ phF,
                                                ushort* __restrict__ phB) {
    int nb = blockIdx.x, ks = blockIdx.y, dz = blockIdx.z;
    const float* W = dz ? Wb : Wf;
    ushort* ph = dz ? phB : phF;
    int tid = threadIdx.x;
    int l = tid >> 3, e = tid & 7;
    int g = nb / 38, ub = nb % 38;
    int u = ub * 16 + (l & 15);
    int k = ks * 32 + (l >> 4) * 8 + e;
    float v = (u < 600 && k < K) ? W[(size_t)(g * 600 + u) * K + k] : 0.f;
    ph[((size_t)nb * NKS + ks) * 512 + tid] = f2bf(v);
}

// ---------------- pack Whh into MFMA fragment-linear layout, hi/lo split
__global__ __launch_bounds__(512) void pack_whh(
    const float* __restrict__ W0f, const float* __restrict__ W0b,
    const float* __restrict__ W1f, const float* __restrict__ W1b,
    ushort* __restrict__ pwh, ushort* __restrict__ pwl) {
    int ub = blockIdx.x, ks = blockIdx.y, ld = blockIdx.z;
    const float* W = (ld == 0) ? W0f : (ld == 1) ? W0b : (ld == 2) ? W1f : W1b;
    int tid = threadIdx.x;
    int l = tid >> 3, e = tid & 7;
    int u = ub * 16 + (l & 15);
    int k = ks * 32 + (l >> 4) * 8 + e;
#pragma unroll
    for (int g = 0; g < 4; ++g) {
        float v = (u < 600 && k < 600) ? W[(size_t)(g * 600 + u) * 600 + k] : 0.f;
        ushort hi = f2bf(v);
        size_t o = ((((size_t)ld * 4 + g) * 38 + ub) * 19 + ks) * 512 + tid;
        pwh[o] = hi;
        pwl[o] = f2bf(v - bf2f(hi));
    }
}

// ---------------- pack biases fragment-linear: [ld(4)][g][ub][lane][4]
__global__ __launch_bounds__(64) void packbias(const float* __restrict__ b0f,
                                               const float* __restrict__ b0b,
                                               const float* __restrict__ b1f,
                                               const float* __restrict__ b1b,
                                               float* __restrict__ bfr) {
    int ub = blockIdx.x, g = blockIdx.y, ld = blockIdx.z;
    const float* b = (ld == 0) ? b0f : (ld == 1) ? b0b : (ld == 2) ? b1f : b1b;
    int lane = threadIdx.x;
    float4 v;
    float* vp = (float*)&v;
#pragma unroll
    for (int r = 0; r < 4; ++r) {
        int u = ub * 16 + (lane >> 4) * 4 + r;
        vp[r] = (u < 600) ? b[g * 600 + u] : 0.f;
    }
    *(float4*)&bfr[((((size_t)ld * 4 + g) * 38 + ub) * 64 + lane) * 4] = v;
}

// ---------------- Wc = W1 @ W2  [1200,4], bc = bm1 @ W2 + bm2  [4]
__global__ void wc_kernel(const float* __restrict__ W1, const float* __restrict__ bm1,
                          const float* __restrict__ W2, const float* __restrict__ bm2,
                          float* __restrict__ Wc, float* __restrict__ bc) {
    int idx = blockIdx.x * 256 + threadIdx.x;
    if (idx < 4800) {
        int k = idx >> 2, l = idx & 3;
        float acc = 0.f;
        for (int j = 0; j < 600; ++j) acc += W1[(size_t)k * 600 + j] * W2[j * 4 + l];
        Wc[idx] = acc;
    }
    if (idx < 4) {
        float acc = bm2[idx];
        for (int j = 0; j < 600; ++j) acc += bm1[j] * W2[j * 4 + idx];
        bc[idx] = acc;
    }
}

// ---------------- bf16 MFMA GEMM (single term), A direct from packed global, B dbuf LDS.
// Output fragment-linear BF16: pre[t][g][ub][nt][lane][4]
#define LOADAG(Ah, KS)                                                           \
    _Pragma("unroll") for (int i = 0; i < 4; ++i) {                              \
        size_t o = ((size_t)(wn16 + i) * NKS + (KS)) * 512 + lane * 8;           \
        Ah[i] = *(const bf16x8*)(Aph + o);                                       \
    }
#define READB(BUF)                                                               \
    _Pragma("unroll") for (int j = 0; j < 4; ++j) {                              \
        bh[j] = *(const bf16x8*)&BsH[BUF][wm + j * 16 + fr][kb8];                \
    }
#define MFALL(Ah)                                                                \
    _Pragma("unroll") for (int i = 0; i < 4; ++i)                                \
        _Pragma("unroll") for (int j = 0; j < 4; ++j)                            \
            acc[i][j] = __builtin_amdgcn_mfma_f32_16x16x32_bf16(Ah[i], bh[j], acc[i][j], 0, 0, 0);

__global__ __launch_bounds__(256) void gemm_mfma(
    const ushort* __restrict__ AphF, const ushort* __restrict__ AphB,
    const ushort* __restrict__ actH,
    int Kp, int NKS, int m_offF, int m_offB,
    ushort* __restrict__ preF, ushort* __restrict__ preB) {
    __shared__ __align__(16) ushort BsH[2][128][40];
    const ushort* Aph = blockIdx.z ? AphB : AphF;
    ushort* preX = blockIdx.z ? preB : preF;
    int m_off = blockIdx.z ? m_offB : m_offF;
    int n0 = blockIdx.x * 128, m0 = blockIdx.y * 128;
    int tid = threadIdx.x, lane = tid & 63, w = tid >> 6;
    int wn16 = (n0 >> 4) + (w >> 1) * 4;
    int wm = (w & 1) * 64;
    int fr = lane & 15, kb8 = (lane >> 4) * 8;
    int srow = tid >> 1, skg = (tid & 1) * 16;
    const ushort* bHrow = actH + (size_t)(m_off + m0 + srow) * Kp + skg;

    uint4 rh0 = *(const uint4*)bHrow, rh1 = *(const uint4*)(bHrow + 8);

    bf16x8 a0h[4], a1h[4], bh[4];
    LOADAG(a0h, 0)

    f32x4 acc[4][4] = {};

    for (int ks = 0; ks < NKS; ks += 2) {
        *(uint4*)&BsH[0][srow][skg] = rh0;
        *(uint4*)&BsH[0][srow][skg + 8] = rh1;
        {
            const ushort* bh_ = bHrow + (ks + 1) * 32;
            rh0 = *(const uint4*)bh_; rh1 = *(const uint4*)(bh_ + 8);
        }
        LOADAG(a1h, ks + 1)
        __syncthreads();
        READB(0)
        MFALL(a0h)
        __syncthreads();
        *(uint4*)&BsH[1][srow][skg] = rh0;
        *(uint4*)&BsH[1][srow][skg + 8] = rh1;
        {
            int ksn = (ks + 2 < NKS) ? ks + 2 : 0;
            const ushort* bh_ = bHrow + ksn * 32;
            rh0 = *(const uint4*)bh_; rh1 = *(const uint4*)(bh_ + 8);
            LOADAG(a0h, ksn)
        }
        __syncthreads();
        READB(1)
        MFALL(a1h)
        __syncthreads();
    }

#pragma unroll
    for (int i = 0; i < 4; ++i) {
        int n16 = wn16 + i;
        int g = n16 / 38, ub = n16 - g * 38;
#pragma unroll
        for (int j = 0; j < 4; ++j) {
            int mloc = m0 + wm + j * 16;
            int tl = mloc >> 6, ntg = (mloc >> 4) & 3;
            ushort* dst = preX + (((((size_t)tl * 4 + g) * 38 + ub) * 4 + ntg) * 64 + lane) * 4;
            ushort4 o;
            o.x = f2bf(acc[i][j][0]);
            o.y = f2bf(acc[i][j][1]);
            o.z = f2bf(acc[i][j][2]);
            o.w = f2bf(acc[i][j][3]);
            *(ushort4*)dst = o;
        }
    }
}

// ---------------- MFMA recurrent step: 76 blocks x 256 (4 waves = 4 batch tiles)
// 3-term hi/lo split; bf16 pre; pre+bias loads hoisted before the MFMA loop.
#define LOADA(Ah, Al, KS)                                                        \
    _Pragma("unroll") for (int g = 0; g < 4; ++g) {                              \
        size_t o = (size_t)(dir * 4 + g) * GSTR + wub + (size_t)(KS)*512 + lane * 8; \
        Ah[g] = *(const bf16x8*)(pwh + o);                                       \
        Al[g] = *(const bf16x8*)(pwl + o);                                       \
    }
#define LOADB1(Bh, Bl, KS)                                                       \
    {                                                                            \
        size_t o = (size_t)(KS)*32 + fk8;                                        \
        Bh = *(const bf16x8*)(hHb + o);                                          \
        Bl = *(const bf16x8*)(hLb + o);                                          \
    }
#define MFT1(Aa, Bb)                                                             \
    _Pragma("unroll") for (int g = 0; g < 4; ++g)                                \
        acc[g] = __builtin_amdgcn_mfma_f32_16x16x32_bf16(Aa[g], Bb, acc[g], 0, 0, 0);
#define MF31(Ah, Al, Bh, Bl) MFT1(Ah, Bh) MFT1(Ah, Bl) MFT1(Al, Bh)

__global__ __launch_bounds__(256) void lstm_step_mfma(
    const ushort* __restrict__ pwh, const ushort* __restrict__ pwl,  // layer base
    const ushort* __restrict__ hInH, const ushort* __restrict__ hInL,
    ushort* __restrict__ hOutH, ushort* __restrict__ hOutL,
    const ushort* __restrict__ preF2, const ushort* __restrict__ preB2,  // bf16 frag-linear
    int tF, int tB,
    const float* __restrict__ biasFr, int layer,
    float* __restrict__ cQ,
    ushort* __restrict__ h0H, int mF, int mB,
    ushort* __restrict__ h1f, ushort* __restrict__ h1b, int oF, int oB, int chunkRows) {
    __shared__ float hsh[4][16][17];
    int tid = threadIdx.x;
    int lane = tid & 63, nt = tid >> 6;
    int blk = blockIdx.x;
    int dir = (blk >= 38) ? 1 : 0;
    int ub = blk - dir * 38;
    int u16 = ub * 16;
    int frow = lane & 15, rr = lane >> 4, fk8 = rr * 8;
    size_t wub = (size_t)ub * 9728;  // ub*19*512
    const ushort* hHb = hInH + ((size_t)dir * 64 + nt * 16 + frow) * 608;
    const ushort* hLb = hInL + ((size_t)dir * 64 + nt * 16 + frow) * 608;

    // ---- hoisted epilogue operand loads (latency hidden under MFMA loop) ----
    const ushort* preX = dir ? preB2 : preF2;
    int t = dir ? tB : tF;
    ushort4 pgu[4];
    float4 bf4[4];
#pragma unroll
    for (int g = 0; g < 4; ++g) {
        pgu[g] = *(const ushort4*)(preX +
            (((((size_t)t * 4 + g) * 38 + ub) * 4 + nt) * 64 + lane) * 4);
        bf4[g] = *(const float4*)(biasFr +
            ((((size_t)(layer * 2 + dir) * 4 + g) * 38 + ub) * 64 + lane) * 4);
    }
    int slot = (dir * 38 + ub) * 4 + nt;
    float* cslot = cQ + ((size_t)slot * 64 + lane) * 4;
    float4 cvec = *(float4*)cslot;
    float* cvp = (float*)&cvec;

    f32x4 acc[4] = {};
    bf16x8 A0h[4], A0l[4], A1h[4], A1l[4];
    bf16x8 B0h, B0l, B1h, B1l;

    LOADA(A0h, A0l, 0)
    LOADB1(B0h, B0l, 0)
    for (int ks = 0; ks < 18; ks += 2) {
        LOADA(A1h, A1l, ks + 1)
        LOADB1(B1h, B1l, ks + 1)
        MF31(A0h, A0l, B0h, B0l)
        LOADA(A0h, A0l, ks + 2)
        LOADB1(B0h, B0l, ks + 2)
        MF31(A1h, A1l, B1h, B1l)
    }
    MF31(A0h, A0l, B0h, B0l)

    // ---- epilogue ----
#pragma unroll
    for (int r = 0; r < 4; ++r) {
        int u = u16 + rr * 4 + r;
        bool valid = (u < 600);
        float gi, gf, gg, go;
        if (valid) {
            const ushort* pp = (const ushort*)&pgu[0];
            gi = acc[0][r] + bf2f(((const ushort*)&pgu[0])[r]) + ((float*)&bf4[0])[r];
            gf = acc[1][r] + bf2f(((const ushort*)&pgu[1])[r]) + ((float*)&bf4[1])[r];
            gg = acc[2][r] + bf2f(((const ushort*)&pgu[2])[r]) + ((float*)&bf4[2])[r];
            go = acc[3][r] + bf2f(((const ushort*)&pgu[3])[r]) + ((float*)&bf4[3])[r];
            (void)pp;
        } else {
            gi = gf = gg = go = 0.f;
        }
        float cv = cvp[r];
        float si = 1.f / (1.f + expf(-gi));
        float sf = 1.f / (1.f + expf(-gf));
        float so = 1.f / (1.f + expf(-go));
        float cn = sf * cv + si * tanhf(gg);
        float hn = so * tanhf(cn);
        cvp[r] = cn;
        hsh[nt][frow][rr * 4 + r] = hn;
    }
    *(float4*)cslot = cvec;
    __syncthreads();

    {
        int bl = lane >> 2, q = lane & 3;
        int b = nt * 16 + bl;
        float v0 = hsh[nt][bl][q * 4 + 0], v1 = hsh[nt][bl][q * 4 + 1];
        float v2 = hsh[nt][bl][q * 4 + 2], v3 = hsh[nt][bl][q * 4 + 3];
        ushort h0_ = f2bf(v0), h1_ = f2bf(v1), h2_ = f2bf(v2), h3_ = f2bf(v3);
        ushort4 hv = {h0_, h1_, h2_, h3_};
        ushort4 lv = {f2bf(v0 - bf2f(h0_)), f2bf(v1 - bf2f(h1_)),
                      f2bf(v2 - bf2f(h2_)), f2bf(v3 - bf2f(h3_))};
        size_t ho = ((size_t)dir * 64 + b) * 608 + u16 + q * 4;
        *(ushort4*)&hOutH[ho] = hv;
        *(ushort4*)&hOutL[ho] = lv;
        if (layer == 0 && (u16 + q * 4 < 600)) {
            size_t so_ = (size_t)((dir ? mB : mF) + b) * KP1 + dir * 600 + u16 + q * 4;
            *(ushort4*)&h0H[so_] = hv;
        }
    }
    if (layer == 1) {
        int u_l = lane & 15, br = (lane >> 4) * 4;
        if (u16 + u_l < 600) {
            ushort4 hv4;
            hv4.x = f2bf(hsh[nt][br + 0][u_l]);
            hv4.y = f2bf(hsh[nt][br + 1][u_l]);
            hv4.z = f2bf(hsh[nt][br + 2][u_l]);
            hv4.w = f2bf(hsh[nt][br + 3][u_l]);
            ushort* op = dir ? h1b : h1f;
            *(ushort4*)&op[(size_t)(u16 + u_l) * chunkRows + (dir ? oB : oF) + nt * 16 + br] = hv4;
        }
    }
}

// ---------------- emission accumulate for one chunk of one direction (bf16 h1)
__global__ __launch_bounds__(256) void emis_add(const ushort* __restrict__ h1C, int cols,
                                                const float* __restrict__ Wc,
                                                const float* __restrict__ bc, int addBias,
                                                float* __restrict__ ys, int t0) {
    int lane = threadIdx.x & 63;
    int l = __builtin_amdgcn_readfirstlane(threadIdx.x >> 6);
    int tl = blockIdx.x;
    float acc = addBias ? bc[l] : 0.f;
    for (int k = 0; k < H_; ++k)
        acc = fmaf(bf2f(h1C[(size_t)k * cols + tl * 64 + lane]), Wc[k * 4 + l], acc);
    int t = t0 + tl, b = lane;
    ys[((size_t)b * T_ + t) * 4 + l] += acc;
}

// ---------------- CRF log-likelihood per batch
__global__ void crf_fwd(const float* __restrict__ ys, const int* __restrict__ ls,
                        const float* __restrict__ trans, const float* __restrict__ startT,
                        const float* __restrict__ endT, float* __restrict__ llb) {
    int b = blockIdx.x;
    int lane = threadIdx.x;
    float acc = 0.f;
    for (int t = lane; t < T_; t += 64) {
        int tg = ls[b * T_ + t];
        acc += ys[((size_t)b * T_ + t) * 4 + tg];
        if (t > 0) acc += trans[ls[b * T_ + t - 1] * 4 + tg];
    }
    for (int off = 32; off; off >>= 1) acc += __shfl_down(acc, off);
    float num = 0.f;
    if (lane == 0) num = startT[ls[b * T_]] + acc + endT[ls[b * T_ + T_ - 1]];

    float a = -1e30f;
    if (lane < 4) a = startT[lane] + ys[((size_t)b * T_) * 4 + lane];
    for (int t = 1; t < T_; ++t) {
        float a0 = __shfl(a, 0), a1 = __shfl(a, 1), a2 = __shfl(a, 2), a3 = __shfl(a, 3);
        if (lane < 4) {
            float v0 = a0 + trans[0 * 4 + lane];
            float v1 = a1 + trans[1 * 4 + lane];
            float v2 = a2 + trans[2 * 4 + lane];
            float v3 = a3 + trans[3 * 4 + lane];
            float mx = fmaxf(fmaxf(v0, v1), fmaxf(v2, v3));
            float ssum = expf(v0 - mx) + expf(v1 - mx) + expf(v2 - mx) + expf(v3 - mx);
            a = mx + logf(ssum) + ys[((size_t)b * T_ + t) * 4 + lane];
        }
    }
    float a0 = __shfl(a, 0), a1 = __shfl(a, 1), a2 = __shfl(a, 2), a3 = __shfl(a, 3);
    if (lane == 0) {
        float v0 = a0 + endT[0], v1 = a1 + endT[1], v2 = a2 + endT[2], v3 = a3 + endT[3];
        float mx = fmaxf(fmaxf(v0, v1), fmaxf(v2, v3));
        float den = mx + logf(expf(v0 - mx) + expf(v1 - mx) + expf(v2 - mx) + expf(v3 - mx));
        llb[b] = num - den;
    }
}

__global__ void final_loss(const float* __restrict__ llb, float* __restrict__ out) {
    int lane = threadIdx.x;
    float v = llb[lane];
    for (int off = 32; off; off >>= 1) v += __shfl_down(v, off);
    if (lane == 0) out[0] = -v / 64.0f;
}

// ---------------- Viterbi decode (tags written as float at out[1..])
__global__ void viterbi(const float* __restrict__ ys, const float* __restrict__ trans,
                        const float* __restrict__ startT, const float* __restrict__ endT,
                        float* __restrict__ out) {
    __shared__ unsigned char bp[T_ * 4];
    int b = blockIdx.x;
    int lane = threadIdx.x;
    float a = -1e30f;
    if (lane < 4) a = startT[lane] + ys[((size_t)b * T_) * 4 + lane];
    for (int t = 1; t < T_; ++t) {
        float a0 = __shfl(a, 0), a1 = __shfl(a, 1), a2 = __shfl(a, 2), a3 = __shfl(a, 3);
        if (lane < 4) {
            float av[4] = {a0, a1, a2, a3};
            float best = av[0] + trans[lane];
            int bi = 0;
            for (int lp = 1; lp < 4; ++lp) {
                float v = av[lp] + trans[lp * 4 + lane];
                if (v > best) { best = v; bi = lp; }
            }
            bp[t * 4 + lane] = (unsigned char)bi;
            a = best + ys[((size_t)b * T_ + t) * 4 + lane];
        }
    }
    float a0 = __shfl(a, 0), a1 = __shfl(a, 1), a2 = __shfl(a, 2), a3 = __shfl(a, 3);
    if (lane == 0) {
        float v[4] = {a0 + endT[0], a1 + endT[1], a2 + endT[2], a3 + endT[3]};
        int tag = 0;
        float best = v[0];
        for (int l = 1; l < 4; ++l)
            if (v[l] > best) { best = v[l]; tag = l; }
        out[1 + b * T_ + (T_ - 1)] = (float)tag;
        for (int t = T_ - 1; t >= 1; --t) {
            tag = bp[t * 4 + tag];
            out[1 + b * T_ + t - 1] = (float)tag;
        }
    }
}

extern "C" void kernel_launch(void* const* d_in, const int* in_sizes, int n_in,
                              void* d_out, int out_size, void* d_ws, size_t ws_size,
                              hipStream_t stream) {
    const int* us = (const int*)d_in[0];
    const int* ls = (const int*)d_in[1];
    const float* embed = (const float*)d_in[2];
    const float* Wih0f = (const float*)d_in[3];
    const float* Whh0f = (const float*)d_in[4];
    const float* b0f   = (const float*)d_in[5];
    const float* Wih0b = (const float*)d_in[6];
    const float* Whh0b = (const float*)d_in[7];
    const float* b0b   = (const float*)d_in[8];
    const float* Wih1f = (const float*)d_in[9];
    const float* Whh1f = (const float*)d_in[10];
    const float* b1f   = (const float*)d_in[11];
    const float* Wih1b = (const float*)d_in[12];
    const float* Whh1b = (const float*)d_in[13];
    const float* b1b   = (const float*)d_in[14];
    const float* W1    = (const float*)d_in[15];
    const float* bm1   = (const float*)d_in[16];
    const float* W2    = (const float*)d_in[17];
    const float* bm2   = (const float*)d_in[18];
    const float* trans = (const float*)d_in[19];
    const float* startT= (const float*)d_in[20];
    const float* endT  = (const float*)d_in[21];
    float* out = (float*)d_out;

    char* p = (char*)d_ws;
    auto alloc = [&](size_t bytes) {
        char* r = p;
        p += (bytes + 255) & ~(size_t)255;
        return r;
    };
    ushort* xspH = (ushort*)alloc((size_t)MTOT * E_ * 2);       // 16.8 MB
    ushort* h0spH = (ushort*)alloc((size_t)MTOT * KP1 * 2);     // 79.7 MB
    ushort* pw0hf = (ushort*)alloc((size_t)152 * 8 * 512 * 2);
    ushort* pw0hb = (ushort*)alloc((size_t)152 * 8 * 512 * 2);
    ushort* pw1hf = (ushort*)alloc((size_t)152 * 38 * 512 * 2);
    ushort* pw1hb = (ushort*)alloc((size_t)152 * 38 * 512 * 2);
    ushort* pwh = (ushort*)alloc((size_t)16 * GSTR * 2);
    ushort* pwl = (ushort*)alloc((size_t)16 * GSTR * 2);
    ushort* hTh = (ushort*)alloc((size_t)2 * PARS * 2);  // [par][dir][b][k]
    ushort* hTl = (ushort*)alloc((size_t)2 * PARS * 2);
    float* cQ  = (float*)alloc((size_t)304 * 64 * 4 * 4);
    float* biasFr = (float*)alloc((size_t)4 * 4 * 38 * 64 * 4 * 4);
    float* Wc  = (float*)alloc(4800 * 4);
    float* bc  = (float*)alloc(4 * 4);
    float* ysb = (float*)alloc((size_t)B_ * T_ * 4 * 4);
    float* llb = (float*)alloc(64 * 4);

    size_t used = (size_t)(p - (char*)d_ws);
    // per-Tc bytes: bf16 pre (2 dirs x 2432*64*2) + bf16 h1 chunks (2 x 600*64*2)
    size_t perTc = (size_t)2 * 2432 * 64 * 2 + (size_t)2 * H_ * 64 * 2;
    int Tc = 512;
    while (Tc > 8 && used + (size_t)Tc * perTc + 4096 > ws_size) Tc >>= 1;
    ushort* preF = (ushort*)alloc((size_t)Tc * 2432 * 64 * 2);
    ushort* preB = (ushort*)alloc((size_t)Tc * 2432 * 64 * 2);
    ushort* h1fC = (ushort*)alloc((size_t)H_ * Tc * 64 * 2);
    ushort* h1bC = (ushort*)alloc((size_t)H_ * Tc * 64 * 2);
    int nc = T_ / Tc;
    int chunkRows = Tc * 64;

    xsplit<<<MTOT, 256, 0, stream>>>(us, embed, xspH);
    pack_wih<<<dim3(152, 8, 2), 512, 0, stream>>>(Wih0f, Wih0b, E_, 8, pw0hf, pw0hb);
    pack_wih<<<dim3(152, 38, 2), 512, 0, stream>>>(Wih1f, Wih1b, 1200, 38, pw1hf, pw1hb);
    pack_whh<<<dim3(38, 19, 4), 512, 0, stream>>>(Whh0f, Whh0b, Whh1f, Whh1b, pwh, pwl);
    packbias<<<dim3(38, 4, 4), 64, 0, stream>>>(b0f, b0b, b1f, b1b, biasFr);
    padzero<<<(MTOT * 16) / 256, 256, 0, stream>>>(h0spH);
    wc_kernel<<<19, 256, 0, stream>>>(W1, bm1, W2, bm2, Wc, bc);
    zero_kernel<<<(B_ * T_ * 4 + 255) / 256, 256, 0, stream>>>(ysb, B_ * T_ * 4);

    for (int layer = 0; layer < 2; ++layer) {
        int Kp = layer ? KP1 : E_;
        int NKS = Kp / 32;
        const ushort* aH = layer ? h0spH : xspH;
        const ushort* AphF = layer ? pw1hf : pw0hf;
        const ushort* AphB = layer ? pw1hb : pw0hb;
        const ushort* pwhL = pwh + (size_t)layer * 8 * GSTR;
        const ushort* pwlL = pwl + (size_t)layer * 8 * GSTR;

        // hTh, hTl, cQ are each exactly PARS(=77824) floats when viewed as f32
        zero3<<<PARS / 256, 256, 0, stream>>>((float*)hTh, (float*)hTl, cQ);

        for (int c = 0; c < nc; ++c) {
            int moffF = c * Tc * 64;
            int moffB = (T_ - (c + 1) * Tc) * 64;
            dim3 gg(NP / 128, chunkRows / 128, 2);
            gemm_mfma<<<gg, 256, 0, stream>>>(AphF, AphB, aH, Kp, NKS, moffF, moffB,
                                              preF, preB);
            for (int s = 0; s < Tc; ++s) {
                int step = c * Tc + s;
                int par = step & 1;
                lstm_step_mfma<<<76, 256, 0, stream>>>(
                    pwhL, pwlL,
                    hTh + (size_t)par * PARS, hTl + (size_t)par * PARS,
                    hTh + (size_t)(par ^ 1) * PARS, hTl + (size_t)(par ^ 1) * PARS,
                    preF, preB, s, Tc - 1 - s,
                    biasFr, layer, cQ,
                    h0spH, step * 64, (T_ - 1 - step) * 64,
                    h1fC, h1bC, s * 64, (Tc - 1 - s) * 64, chunkRows);
            }
            if (layer == 1) {
                emis_add<<<Tc, 256, 0, stream>>>(h1fC, chunkRows, Wc, bc, 1, ysb, c * Tc);
                emis_add<<<Tc, 256, 0, stream>>>(h1bC, chunkRows, Wc + 600 * 4, bc, 0, ysb,
                                                 T_ - (c + 1) * Tc);
            }
        }
    }

    crf_fwd<<<B_, 64, 0, stream>>>(ysb, ls, trans, startT, endT, llb);
    final_loss<<<1, 64, 0, stream>>>(llb, out);
    viterbi<<<B_, 64, 0, stream>>>(ysb, trans, startT, endT, out);
}